// Round 4
// baseline (216.873 us; speedup 1.0000x reference)
//
#include <hip/hip_runtime.h>
#include <math.h>

#define BB 4096
#define LL 50
#define NN 50
#define DD 128
#define GG 4            // batches per block

typedef short bf16x8 __attribute__((ext_vector_type(8)));   // 8 bf16 = 4 VGPRs
typedef float f32x4  __attribute__((ext_vector_type(4)));

static __device__ inline unsigned short f32_to_bf16_rne(float f) {
    unsigned int u = __float_as_uint(f);
    u += 0x7FFFu + ((u >> 16) & 1u);   // round-nearest-even
    return (unsigned short)(u >> 16);
}
static __device__ inline float bf16_to_f32(unsigned short h) {
    return __uint_as_float(((unsigned int)h) << 16);
}

// Combined B fragments for mfma_f32_16x16x32_bf16 over extended K=256:
//   kk 0..3 -> W_seq rows, kk 4..7 -> W_last rows.
// ws[((kk*8+nt)*64+lane)*8+j] = W[(kk&3)*32+(lane>>4)*8+j][nt*16+(lane&15)]
__global__ void prep_w(const float* __restrict__ W_seq,
                       const float* __restrict__ W_last,
                       unsigned short* __restrict__ ws)
{
    int t = blockIdx.x * blockDim.x + threadIdx.x;   // 0..4095
    int lane = t & 63;
    int nt   = (t >> 6) & 7;
    int kk   = t >> 9;
    const float* W = (kk < 4) ? W_seq : W_last;
    int kb = (kk & 3) * 32 + (lane >> 4) * 8;
    int n  = nt * 16 + (lane & 15);
    unsigned short* dst = ws + (size_t)t * 8;
    #pragma unroll
    for (int j = 0; j < 8; ++j)
        dst[j] = f32_to_bf16_rne(W[(kb + j) * DD + n]);
}

// 1024 blocks x 4 batches. 4 waves; wave w owns n-tiles {2w,2w+1} x all m-tiles.
__global__ __launch_bounds__(256, 4) void sess_attn(
    const int*   __restrict__ seq_idx,   // [B,L]
    const int*   __restrict__ mask,      // [B,L]
    const float* __restrict__ nodes,     // [B,N,D]
    const float* __restrict__ b_seq,     // [D]
    const float* __restrict__ W_alpha,   // [D]
    const unsigned short* __restrict__ wfrag,  // d_ws, combined B-frags
    float*       __restrict__ out)       // [B*D] v_n, then [B*D] session_graph
{
    const int tid  = threadIdx.x;
    const int lane = tid & 63;
    const int wave = tid >> 6;
    const int col  = lane & 15;
    const int quad = lane >> 4;
    const int b0   = blockIdx.x * GG;

    __shared__ __align__(16) unsigned short s_nbf[2][64][136];  // 2x17408 B
    __shared__ float s_alpha[2][64];
    __shared__ float s_cntf[2][64];
    __shared__ float s_b[DD];
    __shared__ float s_wa[DD];
    __shared__ int   s_last[2];

    // ---- Prefetch all 16 B-fragments into registers (L2-resident table).
    // Independent of all LDS/barriers: in flight during staging.
    const bf16x8* wsf = (const bf16x8*)wfrag;
    bf16x8 bfrag[16];
    #pragma unroll
    for (int kk = 0; kk < 8; ++kk)
        #pragma unroll
        for (int j = 0; j < 2; ++j)
            bfrag[kk * 2 + j] = wsf[(size_t)((kk * 8 + wave * 2 + j) * 64 + lane)];

    if (tid < DD) { s_b[tid] = b_seq[tid]; s_wa[tid] = W_alpha[tid]; }

    // ---- Prefetch mask/idx rows for all GG batches (wave 0 only uses them).
    int pm[GG], pi[GG];
    if (tid < 64) {
        #pragma unroll
        for (int g = 0; g < GG; ++g) {
            int bg = b0 + g;
            pm[g] = (tid < LL) ? mask[bg * LL + tid]    : 0;
            pi[g] = (tid < LL) ? seq_idx[bg * LL + tid] : 0;
        }
    }

    for (int g = 0; g < GG; ++g) {
        const int b = b0 + g;
        const int p = g & 1;
        const float* nb = nodes + (size_t)b * (NN * DD);

        if (tid < 64) { s_alpha[p][tid] = 0.f; s_cntf[p][tid] = 0.f; }

        // Stage nodes[b] -> bf16 LDS tile (convert in registers).
        for (int i = tid; i < NN * DD / 4; i += 256) {
            float4 v = ((const float4*)nb)[i];
            int r = i >> 5, c = (i & 31) * 4;
            ushort4 h;
            h.x = f32_to_bf16_rne(v.x);
            h.y = f32_to_bf16_rne(v.y);
            h.z = f32_to_bf16_rne(v.z);
            h.w = f32_to_bf16_rne(v.w);
            *(ushort4*)&s_nbf[p][r][c] = h;
        }

        // Wave 0: seq_len, last index, histogram.
        if (tid < 64) {
            int mm = pm[g];
            mm += __shfl_xor(mm, 1);  mm += __shfl_xor(mm, 2);
            mm += __shfl_xor(mm, 4);  mm += __shfl_xor(mm, 8);
            mm += __shfl_xor(mm, 16); mm += __shfl_xor(mm, 32);
            int j = mm - 1;
            if (j < 0) j += LL;                 // JAX negative-index wrap
            int li = __shfl(pi[g], j);          // seq_idx[b][j] from lane j
            if (tid == 0) s_last[p] = li;
            if (tid < LL && pm[g]) atomicAdd(&s_cntf[p][pi[g]], (float)pm[g]);
        }
        __syncthreads();   // tile, alpha/cnt init, s_last ready

        const int last = s_last[p];

        // v_n output: exact fp32 (L2-hot row re-read).
        if (tid < DD) out[(size_t)b * DD + tid] = nb[last * DD + tid];

        // MFMA over extended K=256.
        f32x4 acc[4][2];
        #pragma unroll
        for (int m = 0; m < 4; ++m)
            #pragma unroll
            for (int j = 0; j < 2; ++j)
                acc[m][j] = (f32x4){0.f, 0.f, 0.f, 0.f};

        #pragma unroll
        for (int kk = 0; kk < 8; ++kk) {
            bf16x8 a[4];
            if (kk < 4) {
                #pragma unroll
                for (int m = 0; m < 4; ++m)
                    a[m] = *(const bf16x8*)&s_nbf[p][m * 16 + col][kk * 32 + quad * 8];
            } else {
                bf16x8 av = *(const bf16x8*)&s_nbf[p][last][(kk - 4) * 32 + quad * 8];
                a[0] = av; a[1] = av; a[2] = av; a[3] = av;
            }
            #pragma unroll
            for (int j = 0; j < 2; ++j) {
                #pragma unroll
                for (int m = 0; m < 4; ++m)
                    acc[m][j] = __builtin_amdgcn_mfma_f32_16x16x32_bf16(
                        a[m], bfrag[kk * 2 + j], acc[m][j], 0, 0, 0);
            }
        }

        // Epilogue: alpha[row] += sigmoid(x+b)*W_alpha over this wave's cols.
        #pragma unroll
        for (int m = 0; m < 4; ++m) {
            float pr[4] = {0.f, 0.f, 0.f, 0.f};
            #pragma unroll
            for (int j = 0; j < 2; ++j) {
                int n = (wave * 2 + j) * 16 + col;
                float bb = s_b[n];
                float wa = s_wa[n];
                #pragma unroll
                for (int r = 0; r < 4; ++r) {
                    float x = acc[m][j][r] + bb;
                    float sig = 1.f / (1.f + __expf(-x));
                    pr[r] = fmaf(sig, wa, pr[r]);
                }
            }
            #pragma unroll
            for (int r = 0; r < 4; ++r) {
                float v = pr[r];
                v += __shfl_xor(v, 1);
                v += __shfl_xor(v, 2);
                v += __shfl_xor(v, 4);
                v += __shfl_xor(v, 8);
                int row = m * 16 + quad * 4 + r;
                if (col == 0 && row < NN) atomicAdd(&s_alpha[p][row], v);
            }
        }
        __syncthreads();   // s_alpha complete

        // session_graph[d] = sum_n cnt[n]*alpha[n]*nodes_bf16[n][d]
        if (tid < DD) {
            float acc2 = 0.f;
            #pragma unroll 10
            for (int n = 0; n < NN; ++n)
                acc2 = fmaf(s_cntf[p][n] * s_alpha[p][n],
                            bf16_to_f32(s_nbf[p][n][tid]), acc2);
            out[(size_t)BB * DD + (size_t)b * DD + tid] = acc2;
        }
        // Next iteration uses the other buffer; reuse of this one is fenced
        // by the two barriers of iteration g+1.
    }
}

extern "C" void kernel_launch(void* const* d_in, const int* in_sizes, int n_in,
                              void* d_out, int out_size, void* d_ws, size_t ws_size,
                              hipStream_t stream) {
    const int*   seq     = (const int*)  d_in[0];
    const int*   mask    = (const int*)  d_in[1];
    const float* nodes   = (const float*)d_in[2];
    // d_in[3] = batch_size scalar (shapes compile-time fixed)
    const float* W_last  = (const float*)d_in[4];
    const float* W_seq   = (const float*)d_in[5];
    const float* b_seq   = (const float*)d_in[6];
    const float* W_alpha = (const float*)d_in[7];
    float*       out     = (float*)      d_out;

    unsigned short* wsf = (unsigned short*)d_ws;   // 64 KB combined B-fragments

    prep_w<<<16, 256, 0, stream>>>(W_seq, W_last, wsf);
    sess_attn<<<BB / GG, 256, 0, stream>>>(seq, mask, nodes, b_seq, W_alpha, wsf, out);
}

// Round 5
// 177.301 us; speedup vs baseline: 1.2232x; 1.2232x over previous
//
#include <hip/hip_runtime.h>
#include <math.h>

#define BB 4096
#define LL 50
#define NN 50
#define DD 128
#define STR 136    // LDS row stride in shorts (272 B, 16B-aligned rows)

typedef short bf16x8 __attribute__((ext_vector_type(8)));   // 8 bf16 = 4 VGPRs
typedef float f32x4  __attribute__((ext_vector_type(4)));

static __device__ inline unsigned short f32_to_bf16_rne(float f) {
    unsigned int u = __float_as_uint(f);
    u += 0x7FFFu + ((u >> 16) & 1u);   // round-nearest-even
    return (unsigned short)(u >> 16);
}
static __device__ inline float bf16_to_f32(unsigned short h) {
    return __uint_as_float(((unsigned int)h) << 16);
}

// Combined B fragments for mfma_f32_16x16x32_bf16 over extended K=256:
//   kk 0..3 -> W_seq rows, kk 4..7 -> W_last rows.
// ws[((kk*8+nt)*64+lane)*8+j] = W[(kk&3)*32+(lane>>4)*8+j][nt*16+(lane&15)]
__global__ void prep_w(const float* __restrict__ W_seq,
                       const float* __restrict__ W_last,
                       unsigned short* __restrict__ ws)
{
    int t = blockIdx.x * blockDim.x + threadIdx.x;   // 0..4095
    int lane = t & 63;
    int nt   = (t >> 6) & 7;
    int kk   = t >> 9;
    const float* W = (kk < 4) ? W_seq : W_last;
    int kb = (kk & 3) * 32 + (lane >> 4) * 8;
    int n  = nt * 16 + (lane & 15);
    unsigned short* dst = ws + (size_t)t * 8;
    #pragma unroll
    for (int j = 0; j < 8; ++j)
        dst[j] = f32_to_bf16_rne(W[(kb + j) * DD + n]);
}

// 4096 blocks x 1 batch. 4 waves; wave w owns n-tiles {2w,2w+1}, all m-tiles.
// Load-first structure: every global load issued before any dependent use.
__global__ __launch_bounds__(256, 3) void sess_attn(
    const int*   __restrict__ seq_idx,   // [B,L]
    const int*   __restrict__ mask,      // [B,L]
    const float* __restrict__ nodes,     // [B,N,D]
    const float* __restrict__ b_seq,     // [D]
    const float* __restrict__ W_alpha,   // [D]
    const unsigned short* __restrict__ wfrag,  // d_ws, combined B-frags
    float*       __restrict__ out)       // [B*D] v_n, then [B*D] session_graph
{
    const int b    = blockIdx.x;
    const int tid  = threadIdx.x;
    const int lane = tid & 63;
    const int wave = tid >> 6;
    const int col  = lane & 15;
    const int quad = lane >> 4;

    // rows 50..63 never written; their alpha rows are discarded (row<NN check)
    __shared__ __align__(16) unsigned short s_nbf[64][STR];  // 17408 B
    __shared__ float s_alpha[64];
    __shared__ float s_cntf[64];
    __shared__ int   s_last;

    // ---- Issue ALL global loads up front (independent, all in flight). ----
    // 1) node tile: 1600 float4 over 256 threads (tid<64 take a 7th).
    const float4* nb4 = (const float4*)(nodes + (size_t)b * (NN * DD));
    float4 v[7];
    #pragma unroll
    for (int j = 0; j < 6; ++j) v[j] = nb4[tid + j * 256];
    if (tid < 64) v[6] = nb4[tid + 1536];

    // 2) B fragments (L2-resident table): 8 for W_seq, 8 for W_last.
    const bf16x8* wsf = (const bf16x8*)wfrag;
    bf16x8 bfS[8], bfL[8];
    #pragma unroll
    for (int kk = 0; kk < 4; ++kk)
        #pragma unroll
        for (int j = 0; j < 2; ++j) {
            bfS[kk * 2 + j] = wsf[(size_t)(((kk    ) * 8 + wave * 2 + j) * 64 + lane)];
            bfL[kk * 2 + j] = wsf[(size_t)(((kk + 4) * 8 + wave * 2 + j) * 64 + lane)];
        }

    // 3) mask/idx row (wave 0 consumes).
    int pm = 0, pi = 0;
    if (tid < 64) {
        pm = (tid < LL) ? mask[b * LL + tid]    : 0;
        pi = (tid < LL) ? seq_idx[b * LL + tid] : 0;
    }

    // 4) per-lane epilogue scalars (bias folded into accV init).
    float bb_r[2], wa_r[2];
    #pragma unroll
    for (int j = 0; j < 2; ++j) {
        int n = (wave * 2 + j) * 16 + col;
        bb_r[j] = b_seq[n];
        wa_r[j] = W_alpha[n];
    }

    if (tid < 64) { s_alpha[tid] = 0.f; s_cntf[tid] = 0.f; }

    // ---- Convert + LDS-write the node tile (bf16). ----
    #pragma unroll
    for (int j = 0; j < 6; ++j) {
        int idx = tid + j * 256;
        int r = idx >> 5, c = (idx & 31) * 4;
        ushort4 h;
        h.x = f32_to_bf16_rne(v[j].x);
        h.y = f32_to_bf16_rne(v[j].y);
        h.z = f32_to_bf16_rne(v[j].z);
        h.w = f32_to_bf16_rne(v[j].w);
        *(ushort4*)&s_nbf[r][c] = h;
    }
    if (tid < 64) {
        int idx = tid + 1536;
        int r = idx >> 5, c = (idx & 31) * 4;
        ushort4 h;
        h.x = f32_to_bf16_rne(v[6].x);
        h.y = f32_to_bf16_rne(v[6].y);
        h.z = f32_to_bf16_rne(v[6].z);
        h.w = f32_to_bf16_rne(v[6].w);
        *(ushort4*)&s_nbf[r][c] = h;
    }

    // ---- Wave 0: seq_len, last index, histogram. ----
    if (tid < 64) {
        int mm = pm;
        mm += __shfl_xor(mm, 1);  mm += __shfl_xor(mm, 2);
        mm += __shfl_xor(mm, 4);  mm += __shfl_xor(mm, 8);
        mm += __shfl_xor(mm, 16); mm += __shfl_xor(mm, 32);
        int j = mm - 1;
        if (j < 0) j += LL;                 // JAX negative-index wrap
        int li = __shfl(pi, j);
        if (tid == 0) s_last = li;
        if (tid < LL && pm) atomicAdd(&s_cntf[pi], (float)pm);
    }
    __syncthreads();   // tile, s_last, s_cntf, s_alpha init visible

    const int last = s_last;

    // v_n output: exact fp32 (L2-hot), independent of MFMA below.
    if (tid < DD)
        out[(size_t)b * DD + tid] = nodes[(size_t)b * (NN * DD) + last * DD + tid];

    // ---- MFMA. acc: W_seq part per m-tile; accV: W_last part once (rows
    // of its A-tile are all v_n, so one tile serves every m). Bias in init.
    f32x4 acc[4][2];
    #pragma unroll
    for (int m = 0; m < 4; ++m)
        #pragma unroll
        for (int j = 0; j < 2; ++j)
            acc[m][j] = (f32x4){0.f, 0.f, 0.f, 0.f};
    f32x4 accV[2];
    #pragma unroll
    for (int j = 0; j < 2; ++j)
        accV[j] = (f32x4){bb_r[j], bb_r[j], bb_r[j], bb_r[j]};

    #pragma unroll
    for (int kk = 0; kk < 4; ++kk) {
        bf16x8 a[4];
        #pragma unroll
        for (int m = 0; m < 4; ++m)
            a[m] = *(const bf16x8*)&s_nbf[m * 16 + col][kk * 32 + quad * 8];
        bf16x8 av = *(const bf16x8*)&s_nbf[last][kk * 32 + quad * 8];
        #pragma unroll
        for (int j = 0; j < 2; ++j) {
            #pragma unroll
            for (int m = 0; m < 4; ++m)
                acc[m][j] = __builtin_amdgcn_mfma_f32_16x16x32_bf16(
                    a[m], bfS[kk * 2 + j], acc[m][j], 0, 0, 0);
            accV[j] = __builtin_amdgcn_mfma_f32_16x16x32_bf16(
                av, bfL[kk * 2 + j], accV[j], 0, 0, 0);
        }
    }

    // ---- Epilogue: alpha[row] += sum_cols sigmoid(acc+accV)*W_alpha. ----
    // C layout: col = lane&15, row = m*16 + quad*4 + r.
    #pragma unroll
    for (int m = 0; m < 4; ++m) {
        float pr[4] = {0.f, 0.f, 0.f, 0.f};
        #pragma unroll
        for (int j = 0; j < 2; ++j) {
            float wa = wa_r[j];
            #pragma unroll
            for (int r = 0; r < 4; ++r) {
                float x = acc[m][j][r] + accV[j][r];
                float sig = 1.f / (1.f + __expf(-x));
                pr[r] = fmaf(sig, wa, pr[r]);
            }
        }
        #pragma unroll
        for (int r = 0; r < 4; ++r) {
            float vv = pr[r];
            vv += __shfl_xor(vv, 1);
            vv += __shfl_xor(vv, 2);
            vv += __shfl_xor(vv, 4);
            vv += __shfl_xor(vv, 8);
            int row = m * 16 + quad * 4 + r;
            if (col == 0 && row < NN) atomicAdd(&s_alpha[row], vv);
        }
    }
    __syncthreads();   // s_alpha complete

    // session_graph[d] = sum_n cnt[n]*alpha[n]*nodes_bf16[n][d]
    if (tid < DD) {
        float acc2 = 0.f;
        #pragma unroll 10
        for (int n = 0; n < NN; ++n)
            acc2 = fmaf(s_cntf[n] * s_alpha[n], bf16_to_f32(s_nbf[n][tid]), acc2);
        out[(size_t)BB * DD + (size_t)b * DD + tid] = acc2;
    }
}

extern "C" void kernel_launch(void* const* d_in, const int* in_sizes, int n_in,
                              void* d_out, int out_size, void* d_ws, size_t ws_size,
                              hipStream_t stream) {
    const int*   seq     = (const int*)  d_in[0];
    const int*   mask    = (const int*)  d_in[1];
    const float* nodes   = (const float*)d_in[2];
    // d_in[3] = batch_size scalar (shapes compile-time fixed)
    const float* W_last  = (const float*)d_in[4];
    const float* W_seq   = (const float*)d_in[5];
    const float* b_seq   = (const float*)d_in[6];
    const float* W_alpha = (const float*)d_in[7];
    float*       out     = (float*)      d_out;

    unsigned short* wsf = (unsigned short*)d_ws;   // 64 KB combined B-fragments

    prep_w<<<16, 256, 0, stream>>>(W_seq, W_last, wsf);
    sess_attn<<<BB, 256, 0, stream>>>(seq, mask, nodes, b_seq, W_alpha, wsf, out);
}